// Round 1
// baseline (235.163 us; speedup 1.0000x reference)
//
#include <hip/hip_runtime.h>

#define NP 81
#define CC 128
#define HH 128
#define WW 256
#define TX 64

typedef __attribute__((ext_vector_type(8))) short short8;
typedef __attribute__((ext_vector_type(4))) float f32x4;

__device__ __forceinline__ short f2bf(float f) {
    unsigned int u = __builtin_bit_cast(unsigned int, f);
    u += 0x7fffu + ((u >> 16) & 1u);   // round-to-nearest-even
    return (short)(u >> 16);
}

// Gram-band correlation: per (b, y, x-tile of 64), all 81 displacements.
// Wave w handles A-subtile x0 = X0 + 16*w; per di, two B-tiles at x' offsets
// -4 and +12 cover the 9-wide diagonal band: dj = n - m + 16*t (disjoint).
__global__ __launch_bounds__(256) void corr_mfma_kernel(
        const float* __restrict__ t1, const float* __restrict__ t2,
        float* __restrict__ out) {
    const int id = blockIdx.x;
    const int xt = id & 3;
    const int y  = (id >> 2) & (HH - 1);
    const int b  = id >> 9;
    const int X0 = xt * TX;

    const int tid  = threadIdx.x;
    const int lane = tid & 63;
    const int wv   = tid >> 6;     // wave index 0..3 -> A-subtile
    const int n    = lane & 15;    // MFMA n / m-row-index within fragment
    const int q    = lane >> 4;    // k-group

    // sA: [64 x][40 shorts] (32 used + 8 pad -> 80B stride, 16B aligned)
    // sB: [9 di][80 x'][40 shorts]
    __shared__ short smem[2560 + 28800];
    short* sA = smem;
    short* sB = smem + 2560;

    f32x4 acc[9][2];
#pragma unroll
    for (int i = 0; i < 9; i++)
#pragma unroll
        for (int t = 0; t < 2; t++) acc[i][t] = (f32x4){0.f, 0.f, 0.f, 0.f};

    const size_t plane = (size_t)HH * WW;
    const float* t1b = t1 + (size_t)b * CC * plane + (size_t)y * WW;
    const float* t2b = t2 + (size_t)b * CC * plane;

    for (int c0 = 0; c0 < CC; c0 += 32) {
        __syncthreads();
        // ---- stage A tile: 64 x * 32 c, one short8 per thread ----
        {
            const int x  = tid & 63;
            const int cg = tid >> 6;
            const float* p = t1b + (size_t)(c0 + cg * 8) * plane + X0 + x;
            short8 pk;
#pragma unroll
            for (int j = 0; j < 8; j++) pk[j] = f2bf(p[(size_t)j * plane]);
            *(short8*)&sA[x * 40 + cg * 8] = pk;
        }
        // ---- stage B tile: 9 rows * 80 x * 32 c = 2880 short8 units ----
#pragma unroll
        for (int i = 0; i < 12; i++) {
            const int u = tid + i * 256;
            if (u < 2880) {
                const int r   = u / 320;
                const int rem = u - r * 320;
                const int cg  = rem / 80;
                const int ix  = rem - cg * 80;
                const int y2  = y + r - 4;
                const int x2  = X0 - 4 + ix;
                short8 pk;
                if (y2 >= 0 && y2 < HH && x2 >= 0 && x2 < WW) {
                    const float* p = t2b + (size_t)(c0 + cg * 8) * plane
                                   + (size_t)y2 * WW + x2;
#pragma unroll
                    for (int j = 0; j < 8; j++) pk[j] = f2bf(p[(size_t)j * plane]);
                } else {
#pragma unroll
                    for (int j = 0; j < 8; j++) pk[j] = 0;
                }
                *(short8*)&sB[r * 3200 + ix * 40 + cg * 8] = pk;
            }
        }
        __syncthreads();
        // ---- MFMA band compute ----
        const short8 af = *(const short8*)&sA[(16 * wv + n) * 40 + q * 8];
#pragma unroll
        for (int di = 0; di < 9; di++) {
#pragma unroll
            for (int t = 0; t < 2; t++) {
                const short8 bf = *(const short8*)
                    &sB[di * 3200 + (16 * wv + 16 * t + n) * 40 + q * 8];
                acc[di][t] = __builtin_amdgcn_mfma_f32_16x16x32_bf16(
                    af, bf, acc[di][t], 0, 0, 0);
            }
        }
    }

    // ---- epilogue: band-extract through LDS, coalesced float4 stores ----
    __syncthreads();
    float* obuf = (float*)smem;   // [81][68] fp32 (stride 68 keeps 16B align)
#pragma unroll
    for (int di = 0; di < 9; di++)
#pragma unroll
        for (int t = 0; t < 2; t++)
#pragma unroll
            for (int r = 0; r < 4; r++) {
                const int m  = q * 4 + r;           // D row = x within subtile
                const int dj = n - m + 16 * t;      // D col n -> displacement
                if (dj >= 0 && dj <= 8)
                    obuf[(di * 9 + dj) * 68 + 16 * wv + m] = acc[di][t][r];
            }
    __syncthreads();
    float* ob = out + (size_t)b * NP * plane + (size_t)y * WW + X0;
#pragma unroll
    for (int i = 0; i < 6; i++) {
        const int u = tid + i * 256;
        if (u < 1296) {                       // 81 p-rows * 16 float4
            const int p  = u >> 4;
            const int xu = u & 15;
            f32x4 v = *(const f32x4*)&obuf[p * 68 + xu * 4];
            *(f32x4*)&ob[(size_t)p * plane + xu * 4] = v;
        }
    }
}

extern "C" void kernel_launch(void* const* d_in, const int* in_sizes, int n_in,
                              void* d_out, int out_size, void* d_ws, size_t ws_size,
                              hipStream_t stream) {
    const float* t1 = (const float*)d_in[0];
    const float* t2 = (const float*)d_in[1];
    float* out = (float*)d_out;
    // 4 b * 128 y * 4 x-tiles = 2048 blocks; consecutive ids share t2 rows
    corr_mfma_kernel<<<2048, 256, 0, stream>>>(t1, t2, out);
}

// Round 2
// 205.784 us; speedup vs baseline: 1.1428x; 1.1428x over previous
//
#include <hip/hip_runtime.h>

#define NP 81
#define CC 128
#define HH 128
#define WW 256
#define YP 136
#define XP 288
#define WS_NEED 40108032ull   // 32 * 136 * 288 * 32 bytes

typedef __attribute__((ext_vector_type(8))) short short8;
typedef __attribute__((ext_vector_type(4))) float f32x4;
typedef __attribute__((ext_vector_type(16))) float f32x16;

__device__ __forceinline__ short f2bf(float f) {
    unsigned int u = __builtin_bit_cast(unsigned int, f);
    u += 0x7fffu + ((u >> 16) & 1u);   // round-to-nearest-even
    return (short)(u >> 16);
}

// ---- pre-pass: t2 fp32 [b][c][h][w] -> ws bf16 [b][cg8][yp136][xp288][c16],
// halo zero-padded (y offset +4, x offset +4) so main staging is branch-free.
__global__ __launch_bounds__(256) void prepass_t2(const float* __restrict__ t2,
                                                  short* __restrict__ ws) {
    const int u = blockIdx.x * 256 + threadIdx.x;    // exactly 32*136*288 threads
    const int xp = u % XP;
    const int v  = u / XP;
    const int yp = v % YP;
    const int bc = v / YP;                            // b*8 + cg
    const int y2 = yp - 4, x2 = xp - 4;
    short8 lo = {0,0,0,0,0,0,0,0}, hi = {0,0,0,0,0,0,0,0};
    if (y2 >= 0 && y2 < HH && x2 >= 0 && x2 < WW) {
        const int b = bc >> 3, cg = bc & 7;
        const size_t pl = (size_t)HH * WW;
        const float* p = t2 + ((size_t)(b * CC + cg * 16) * HH + y2) * WW + x2;
#pragma unroll
        for (int j = 0; j < 8; j++) lo[j] = f2bf(p[(size_t)j * pl]);
#pragma unroll
        for (int j = 0; j < 8; j++) hi[j] = f2bf(p[(size_t)(j + 8) * pl]);
    }
    short* o = ws + (size_t)u * 16;
    *(short8*)o = lo;
    *(short8*)(o + 8) = hi;
}

// ---- main: 32x32x16 MFMA band scheme; 9 waves/block, wave w owns di = w.
// Per di the 9-wide band dj = n - m + 32t (t=0,1) covers exactly 64 staged x'.
__global__ __launch_bounds__(576) void corr32_kernel(const float* __restrict__ t1,
                                                     const short* __restrict__ ws,
                                                     float* __restrict__ out) {
    const int id = blockIdx.x;
    const int xt = id & 7;
    const int y  = (id >> 3) & (HH - 1);
    const int b  = id >> 10;
    const int X0 = xt * 32;

    const int tid  = threadIdx.x;
    const int lane = tid & 63;
    const int w    = tid >> 6;        // 0..8 = di
    const int n    = lane & 31;       // A row m / B col n
    const int g    = lane >> 5;       // k-group

    // sA: 32 x * 144 shorts (288B stride, 32B pad) = 9216 B
    // sB: 9 rows * 1024 shorts (64 x' * 16 c)      = 18432 B
    __shared__ short smem[4608 + 9216];
    short* sA = smem;
    short* sB = smem + 4608;

    const size_t plane = (size_t)HH * WW;

    // stage A once, full c (only 1x total t1 traffic)
    if (tid < 512) {
        const int x = tid & 31, oct = tid >> 5;     // oct = c/8
        const float* p = t1 + (size_t)(b * CC + oct * 8) * plane
                       + (size_t)y * WW + X0 + x;
        short8 pk;
#pragma unroll
        for (int j = 0; j < 8; j++) pk[j] = f2bf(p[(size_t)j * plane]);
        *(short8*)&sA[x * 144 + oct * 8] = pk;
    }

    f32x16 accv[2];
#pragma unroll
    for (int t = 0; t < 2; ++t)
#pragma unroll
        for (int r = 0; r < 16; ++r) accv[t][r] = 0.f;

    // each thread stages 2 of the 1152 16B-units per chunk
    const int u0 = tid, u1 = tid + 576;
    const int r0 = u0 >> 7, s0 = u0 & 127;
    const int r1 = u1 >> 7, s1 = u1 & 127;
    const size_t base0 = ((size_t)b * 8 * YP + (y + r0)) * XP + X0;   // + kc*YP*XP
    const size_t base1 = ((size_t)b * 8 * YP + (y + r1)) * XP + X0;

    short8 pf0 = *(const short8*)(ws + base0 * 16 + s0 * 8);
    short8 pf1 = *(const short8*)(ws + base1 * 16 + s1 * 8);

    for (int kc = 0; kc < 8; ++kc) {
        __syncthreads();                       // prev chunk fully consumed
        *(short8*)&sB[r0 * 1024 + s0 * 8] = pf0;
        *(short8*)&sB[r1 * 1024 + s1 * 8] = pf1;
        if (kc < 7) {                          // prefetch next chunk (no LDS dep)
            const size_t adv = (size_t)(kc + 1) * YP * XP * 16;
            pf0 = *(const short8*)(ws + base0 * 16 + adv + s0 * 8);
            pf1 = *(const short8*)(ws + base1 * 16 + adv + s1 * 8);
        }
        __syncthreads();                       // chunk kc visible
        const short8 af  = *(const short8*)&sA[n * 144 + kc * 16 + g * 8];
        const short8 bf0 = *(const short8*)&sB[w * 1024 + n * 16 + g * 8];
        const short8 bf1 = *(const short8*)&sB[w * 1024 + (32 + n) * 16 + g * 8];
        accv[0] = __builtin_amdgcn_mfma_f32_32x32x16_bf16(af, bf0, accv[0], 0, 0, 0);
        accv[1] = __builtin_amdgcn_mfma_f32_32x32x16_bf16(af, bf1, accv[1], 0, 0, 0);
    }

    // epilogue: band-extract into LDS, then coalesced float4 stores
    __syncthreads();
    float* obuf = (float*)smem;                // [81][40] fp32
#pragma unroll
    for (int t = 0; t < 2; ++t)
#pragma unroll
        for (int r = 0; r < 16; ++r) {
            const int m  = (r & 3) + 8 * (r >> 2) + 4 * g;  // D row = x offset
            const int dj = n - m + 32 * t;
            if (dj >= 0 && dj <= 8) obuf[(w * 9 + dj) * 40 + m] = accv[t][r];
        }
    __syncthreads();
    for (int u = tid; u < 648; u += 576) {     // 81 p * 8 float4
        const int p = u >> 3, xq = u & 7;
        f32x4 v = *(const f32x4*)&obuf[p * 40 + xq * 4];
        *(f32x4*)&out[((size_t)(b * NP + p) * HH + y) * WW + X0 + xq * 4] = v;
    }
}

// ---------------- fallback (proven R1 kernel) if ws is too small ----------------
__global__ __launch_bounds__(256) void corr_mfma_kernel(
        const float* __restrict__ t1, const float* __restrict__ t2,
        float* __restrict__ out) {
    const int id = blockIdx.x;
    const int xt = id & 3;
    const int y  = (id >> 2) & (HH - 1);
    const int b  = id >> 9;
    const int X0 = xt * 64;
    const int tid  = threadIdx.x;
    const int lane = tid & 63;
    const int wv   = tid >> 6;
    const int n    = lane & 15;
    const int q    = lane >> 4;
    __shared__ short smem[2560 + 28800];
    short* sA = smem;
    short* sB = smem + 2560;
    f32x4 acc[9][2];
#pragma unroll
    for (int i = 0; i < 9; i++)
#pragma unroll
        for (int t = 0; t < 2; t++) acc[i][t] = (f32x4){0.f, 0.f, 0.f, 0.f};
    const size_t plane = (size_t)HH * WW;
    const float* t1b = t1 + (size_t)b * CC * plane + (size_t)y * WW;
    const float* t2b = t2 + (size_t)b * CC * plane;
    for (int c0 = 0; c0 < CC; c0 += 32) {
        __syncthreads();
        {
            const int x  = tid & 63;
            const int cg = tid >> 6;
            const float* p = t1b + (size_t)(c0 + cg * 8) * plane + X0 + x;
            short8 pk;
#pragma unroll
            for (int j = 0; j < 8; j++) pk[j] = f2bf(p[(size_t)j * plane]);
            *(short8*)&sA[x * 40 + cg * 8] = pk;
        }
#pragma unroll
        for (int i = 0; i < 12; i++) {
            const int u = tid + i * 256;
            if (u < 2880) {
                const int r   = u / 320;
                const int rem = u - r * 320;
                const int cg  = rem / 80;
                const int ix  = rem - cg * 80;
                const int y2  = y + r - 4;
                const int x2  = X0 - 4 + ix;
                short8 pk;
                if (y2 >= 0 && y2 < HH && x2 >= 0 && x2 < WW) {
                    const float* p = t2b + (size_t)(c0 + cg * 8) * plane
                                   + (size_t)y2 * WW + x2;
#pragma unroll
                    for (int j = 0; j < 8; j++) pk[j] = f2bf(p[(size_t)j * plane]);
                } else {
#pragma unroll
                    for (int j = 0; j < 8; j++) pk[j] = 0;
                }
                *(short8*)&sB[r * 3200 + ix * 40 + cg * 8] = pk;
            }
        }
        __syncthreads();
        const short8 af = *(const short8*)&sA[(16 * wv + n) * 40 + q * 8];
#pragma unroll
        for (int di = 0; di < 9; di++) {
#pragma unroll
            for (int t = 0; t < 2; t++) {
                const short8 bf = *(const short8*)
                    &sB[di * 3200 + (16 * wv + 16 * t + n) * 40 + q * 8];
                acc[di][t] = __builtin_amdgcn_mfma_f32_16x16x32_bf16(
                    af, bf, acc[di][t], 0, 0, 0);
            }
        }
    }
    __syncthreads();
    float* obuf = (float*)smem;
#pragma unroll
    for (int di = 0; di < 9; di++)
#pragma unroll
        for (int t = 0; t < 2; t++)
#pragma unroll
            for (int r = 0; r < 4; r++) {
                const int m  = q * 4 + r;
                const int dj = n - m + 16 * t;
                if (dj >= 0 && dj <= 8)
                    obuf[(di * 9 + dj) * 68 + 16 * wv + m] = acc[di][t][r];
            }
    __syncthreads();
    float* ob = out + (size_t)b * NP * plane + (size_t)y * WW + X0;
#pragma unroll
    for (int i = 0; i < 6; i++) {
        const int u = tid + i * 256;
        if (u < 1296) {
            const int p  = u >> 4;
            const int xu = u & 15;
            f32x4 v = *(const f32x4*)&obuf[p * 68 + xu * 4];
            *(f32x4*)&ob[(size_t)p * plane + xu * 4] = v;
        }
    }
}

extern "C" void kernel_launch(void* const* d_in, const int* in_sizes, int n_in,
                              void* d_out, int out_size, void* d_ws, size_t ws_size,
                              hipStream_t stream) {
    const float* t1 = (const float*)d_in[0];
    const float* t2 = (const float*)d_in[1];
    float* out = (float*)d_out;
    if (ws_size >= WS_NEED) {
        short* ws = (short*)d_ws;
        prepass_t2<<<4896, 256, 0, stream>>>(t2, ws);     // 4896*256 = 32*136*288
        corr32_kernel<<<4096, 576, 0, stream>>>(t1, ws, out);
    } else {
        corr_mfma_kernel<<<2048, 256, 0, stream>>>(t1, t2, out);
    }
}

// Round 3
// 196.382 us; speedup vs baseline: 1.1975x; 1.0479x over previous
//
#include <hip/hip_runtime.h>

#define NP 81
#define CC 128
#define HH 128
#define WW 256
#define YP 136
#define XP 288
#define WS_NEED 40108032ull   // 32 * 136 * 288 * 32 bytes

typedef __attribute__((ext_vector_type(8))) short short8;
typedef __attribute__((ext_vector_type(4))) float f32x4;
typedef __attribute__((ext_vector_type(16))) float f32x16;

__device__ __forceinline__ short f2bf(float f) {
    unsigned int u = __builtin_bit_cast(unsigned int, f);
    u += 0x7fffu + ((u >> 16) & 1u);   // round-to-nearest-even
    return (short)(u >> 16);
}

// ---- pre-pass: t2 fp32 [b][c][h][w] -> ws bf16 [b][cg8][yp136][xp288][c16],
// halo zero-padded (y offset +4, x offset +4). This IS the B-fragment layout:
// a wave's 64 lanes reading (xp+n)*16 + g*8 is one coalesced 1 KB load.
__global__ __launch_bounds__(256) void prepass_t2(const float* __restrict__ t2,
                                                  short* __restrict__ ws) {
    const int u = blockIdx.x * 256 + threadIdx.x;    // exactly 32*136*288 threads
    const int xp = u % XP;
    const int v  = u / XP;
    const int yp = v % YP;
    const int bc = v / YP;                            // b*8 + cg
    const int y2 = yp - 4, x2 = xp - 4;
    short8 lo = {0,0,0,0,0,0,0,0}, hi = {0,0,0,0,0,0,0,0};
    if (y2 >= 0 && y2 < HH && x2 >= 0 && x2 < WW) {
        const int b = bc >> 3, cg = bc & 7;
        const size_t pl = (size_t)HH * WW;
        const float* p = t2 + ((size_t)(b * CC + cg * 16) * HH + y2) * WW + x2;
#pragma unroll
        for (int j = 0; j < 8; j++) lo[j] = f2bf(p[(size_t)j * pl]);
#pragma unroll
        for (int j = 0; j < 8; j++) hi[j] = f2bf(p[(size_t)(j + 8) * pl]);
    }
    short* o = ws + (size_t)u * 16;
    *(short8*)o = lo;
    *(short8*)(o + 8) = hi;
}

// ---- main: 32x32x16 MFMA band scheme, no sB. 9 waves/block, wave w owns
// di = w and loads its 2 B-fragments per chunk directly from ws (prefetched).
// sA is XOR-swizzled ((c/8) ^ (x&15)) for conflict-free b128 writes & reads.
__global__ __launch_bounds__(576, 7) void corr32_v2(const float* __restrict__ t1,
                                                    const short* __restrict__ ws,
                                                    float* __restrict__ out) {
    const int id = blockIdx.x;
    const int xt = id & 7;
    const int y  = (id >> 3) & (HH - 1);
    const int b  = id >> 10;
    const int X0 = xt * 32;

    const int tid  = threadIdx.x;
    const int lane = tid & 63;
    const int w    = tid >> 6;        // 0..8 = di
    const int n    = lane & 31;       // A row m / B col n
    const int g    = lane >> 5;       // k-group

    __shared__ float smemf[3240];     // epilogue obuf [81][40]; head aliases sA
    short* sA = (short*)smemf;        // 32 x * 128 shorts, XOR-swizzled

    const size_t plane = (size_t)HH * WW;

    // stage A: t1 row y, 32 x, all 128 c (read once, shared by 9 waves)
    if (tid < 512) {
        const int x = tid & 31, oct = tid >> 5;     // oct = c/8
        const float* p = t1 + (size_t)(b * CC + oct * 8) * plane
                       + (size_t)y * WW + X0 + x;
        short8 pk;
#pragma unroll
        for (int j = 0; j < 8; j++) pk[j] = f2bf(p[(size_t)j * plane]);
        *(short8*)&sA[x * 128 + ((oct ^ (x & 15)) * 8)] = pk;
    }

    f32x16 acc[2];
#pragma unroll
    for (int t = 0; t < 2; ++t)
#pragma unroll
        for (int r = 0; r < 16; ++r) acc[t][r] = 0.f;

    // B-fragment global addresses: chunk kc lives at cg=kc in ws
    const size_t cstride = (size_t)YP * XP * 16;          // shorts per c-chunk
    size_t bofs = ((((size_t)b * 8) * YP + (y + w)) * XP + (X0 + n)) * 16 + g * 8;

    short8 c0 = *(const short8*)(ws + bofs);              // t=0 (x' offset -4)
    short8 c1 = *(const short8*)(ws + bofs + 512);        // t=1 (+32 x' = 512 shorts)

    __syncthreads();

#pragma unroll
    for (int kc = 0; kc < 8; ++kc) {
        short8 p0, p1;
        if (kc < 7) {                                     // prefetch next chunk
            p0 = *(const short8*)(ws + bofs + cstride);
            p1 = *(const short8*)(ws + bofs + cstride + 512);
        }
        const short8 af = *(const short8*)
            &sA[n * 128 + (((kc * 2 + g) ^ (n & 15)) * 8)];
        acc[0] = __builtin_amdgcn_mfma_f32_32x32x16_bf16(af, c0, acc[0], 0, 0, 0);
        acc[1] = __builtin_amdgcn_mfma_f32_32x32x16_bf16(af, c1, acc[1], 0, 0, 0);
        if (kc < 7) { c0 = p0; c1 = p1; bofs += cstride; }
    }

    // epilogue: band-extract (dj = n - m + 32t) into LDS, coalesced stores
    __syncthreads();
    float* obuf = smemf;                                  // [81][40] fp32
#pragma unroll
    for (int t = 0; t < 2; ++t)
#pragma unroll
        for (int r = 0; r < 16; ++r) {
            const int m  = (r & 3) + 8 * (r >> 2) + 4 * g;  // D row = x offset
            const int dj = n - m + 32 * t;
            if (dj >= 0 && dj <= 8) obuf[(w * 9 + dj) * 40 + m] = acc[t][r];
        }
    __syncthreads();
    for (int u = tid; u < 648; u += 576) {                // 81 p * 8 float4
        const int p = u >> 3, xq = u & 7;
        f32x4 v = *(const f32x4*)&obuf[p * 40 + xq * 4];
        *(f32x4*)&out[((size_t)(b * NP + p) * HH + y) * WW + X0 + xq * 4] = v;
    }
}

// ---------------- fallback (proven R1 kernel) if ws is too small ----------------
__global__ __launch_bounds__(256) void corr_mfma_kernel(
        const float* __restrict__ t1, const float* __restrict__ t2,
        float* __restrict__ out) {
    const int id = blockIdx.x;
    const int xt = id & 3;
    const int y  = (id >> 2) & (HH - 1);
    const int b  = id >> 9;
    const int X0 = xt * 64;
    const int tid  = threadIdx.x;
    const int lane = tid & 63;
    const int wv   = tid >> 6;
    const int n    = lane & 15;
    const int q    = lane >> 4;
    __shared__ short smem[2560 + 28800];
    short* sA = smem;
    short* sB = smem + 2560;
    f32x4 acc[9][2];
#pragma unroll
    for (int i = 0; i < 9; i++)
#pragma unroll
        for (int t = 0; t < 2; t++) acc[i][t] = (f32x4){0.f, 0.f, 0.f, 0.f};
    const size_t plane = (size_t)HH * WW;
    const float* t1b = t1 + (size_t)b * CC * plane + (size_t)y * WW;
    const float* t2b = t2 + (size_t)b * CC * plane;
    for (int c0 = 0; c0 < CC; c0 += 32) {
        __syncthreads();
        {
            const int x  = tid & 63;
            const int cg = tid >> 6;
            const float* p = t1b + (size_t)(c0 + cg * 8) * plane + X0 + x;
            short8 pk;
#pragma unroll
            for (int j = 0; j < 8; j++) pk[j] = f2bf(p[(size_t)j * plane]);
            *(short8*)&sA[x * 40 + cg * 8] = pk;
        }
#pragma unroll
        for (int i = 0; i < 12; i++) {
            const int u = tid + i * 256;
            if (u < 2880) {
                const int r   = u / 320;
                const int rem = u - r * 320;
                const int cg  = rem / 80;
                const int ix  = rem - cg * 80;
                const int y2  = y + r - 4;
                const int x2  = X0 - 4 + ix;
                short8 pk;
                if (y2 >= 0 && y2 < HH && x2 >= 0 && x2 < WW) {
                    const float* p = t2b + (size_t)(c0 + cg * 8) * plane
                                   + (size_t)y2 * WW + x2;
#pragma unroll
                    for (int j = 0; j < 8; j++) pk[j] = f2bf(p[(size_t)j * plane]);
                } else {
#pragma unroll
                    for (int j = 0; j < 8; j++) pk[j] = 0;
                }
                *(short8*)&sB[r * 3200 + ix * 40 + cg * 8] = pk;
            }
        }
        __syncthreads();
        const short8 af = *(const short8*)&sA[(16 * wv + n) * 40 + q * 8];
#pragma unroll
        for (int di = 0; di < 9; di++) {
#pragma unroll
            for (int t = 0; t < 2; t++) {
                const short8 bf = *(const short8*)
                    &sB[di * 3200 + (16 * wv + 16 * t + n) * 40 + q * 8];
                acc[di][t] = __builtin_amdgcn_mfma_f32_16x16x32_bf16(
                    af, bf, acc[di][t], 0, 0, 0);
            }
        }
    }
    __syncthreads();
    float* obuf = (float*)smem;
#pragma unroll
    for (int di = 0; di < 9; di++)
#pragma unroll
        for (int t = 0; t < 2; t++)
#pragma unroll
            for (int r = 0; r < 4; r++) {
                const int m  = q * 4 + r;
                const int dj = n - m + 16 * t;
                if (dj >= 0 && dj <= 8)
                    obuf[(di * 9 + dj) * 68 + 16 * wv + m] = acc[di][t][r];
            }
    __syncthreads();
    float* ob = out + (size_t)b * NP * plane + (size_t)y * WW + X0;
#pragma unroll
    for (int i = 0; i < 6; i++) {
        const int u = tid + i * 256;
        if (u < 1296) {
            const int p  = u >> 4;
            const int xu = u & 15;
            f32x4 v = *(const f32x4*)&obuf[p * 68 + xu * 4];
            *(f32x4*)&ob[(size_t)p * plane + xu * 4] = v;
        }
    }
}

extern "C" void kernel_launch(void* const* d_in, const int* in_sizes, int n_in,
                              void* d_out, int out_size, void* d_ws, size_t ws_size,
                              hipStream_t stream) {
    const float* t1 = (const float*)d_in[0];
    const float* t2 = (const float*)d_in[1];
    float* out = (float*)d_out;
    if (ws_size >= WS_NEED) {
        short* ws = (short*)d_ws;
        prepass_t2<<<4896, 256, 0, stream>>>(t2, ws);     // 4896*256 = 32*136*288
        corr32_v2<<<4096, 576, 0, stream>>>(t1, ws, out);
    } else {
        corr_mfma_kernel<<<2048, 256, 0, stream>>>(t1, t2, out);
    }
}